// Round 10
// baseline (224.497 us; speedup 1.0000x reference)
//
#include <hip/hip_runtime.h>
#include <hip/hip_bf16.h>
#include <cstddef>

#define TT 50
#define NN 512
#define DIN 3
#define HH 128
#define NPG 64
#define DEGCAP 128

typedef short short8 __attribute__((ext_vector_type(8)));
typedef float f32x4 __attribute__((ext_vector_type(4)));
typedef unsigned short us4 __attribute__((ext_vector_type(4)));

// ---- LDS strides (ushort elems) ----
#define SROW 136
#define VROW 56
#define PROW 72
// attn layout
#define SQ_OFF 0
#define SK_OFF 6800
#define SV_OFF 13600
#define PQ_OFF 20784
#define SMEM_E2 39216      // 78,432 B -> 2 blocks/CU
// proj layout: bufA @0, bufB @6800 (A-frag rows 50..63 overread into bufB: discarded)
#define PB_OFF 6800
#define SMEM_E1 15504      // 31,008 B -> 4 blocks/CU @512thr
// xw2 layout
#define XW_WOFF 17408
#define SMEM_X 34816       // 69,632 B

static __device__ __forceinline__ unsigned short f2b(float f) {
    unsigned int u = __builtin_bit_cast(unsigned int, f);
    unsigned int r = (u + 0x7fffu + ((u >> 16) & 1u)) >> 16;
    return (unsigned short)r;
}
static __device__ __forceinline__ float b2f(unsigned short h) {
    unsigned int u = ((unsigned int)h) << 16;
    return __builtin_bit_cast(float, u);
}

// B-fragment loaders: fp32 (convert) or pre-converted bf16 (direct short8)
__device__ __forceinline__ short8 load_bfrag(const float* W, int row, int k) {
    const float* p = W + (size_t)row * HH + k;
    float4 w0 = *reinterpret_cast<const float4*>(p);
    float4 w1 = *reinterpret_cast<const float4*>(p + 4);
    short8 t;
    t[0] = (short)f2b(w0.x); t[1] = (short)f2b(w0.y);
    t[2] = (short)f2b(w0.z); t[3] = (short)f2b(w0.w);
    t[4] = (short)f2b(w1.x); t[5] = (short)f2b(w1.y);
    t[6] = (short)f2b(w1.z); t[7] = (short)f2b(w1.w);
    return t;
}
__device__ __forceinline__ short8 load_bfrag(const unsigned short* W, int row, int k) {
    return *reinterpret_cast<const short8*>(W + (size_t)row * HH + k);
}

// fp32->bf16 weight conversion over the flat concatenation {Wq,Wk,Wv,W_in,W_out},
// in float4 units. Runs as extra blocks inside the GCN-phase kernels (overlap).
__device__ __forceinline__ void conv_slice(
    const float* Wq, const float* Wk, const float* Wv,
    const float* Wi, const float* Wo, unsigned short* OW,
    long long u0, long long u1, long long stride, long long ctid)
{
    for (long long u = u0 + ctid; u < u1; u += stride) {
        const float4* src; long long l;
        if (u < 2097152LL)       { src = (const float4*)Wq; l = u; }
        else if (u < 4194304LL)  { src = (const float4*)Wk; l = u - 2097152LL; }
        else if (u < 6291456LL)  { src = (const float4*)Wv; l = u - 4194304LL; }
        else if (u < 12582912LL) { src = (const float4*)Wi; l = u - 6291456LL; }
        else                     { src = (const float4*)Wo; l = u - 12582912LL; }
        float4 v = src[l];
        us4 o;
        o[0] = f2b(v.x); o[1] = f2b(v.y); o[2] = f2b(v.z); o[3] = f2b(v.w);
        *reinterpret_cast<us4*>(OW + u * 4) = o;
    }
}

// ---------------------------------------------------------------------------
// A0: ego mask -> MF
// ---------------------------------------------------------------------------
__global__ __launch_bounds__(256) void mf_kernel(
    const int* __restrict__ ego, float* __restrict__ MF)
{
    const int idx = blockIdx.x * 256 + threadIdx.x;
    const int t = idx >> 9;
    const int i = idx & 511;
    const int b = i >> 6, p = i & 63;
    MF[idx] = (ego[b * (TT * NPG) + t * NPG + p] != 0) ? 1.0f : 0.0f;
}

// ---------------------------------------------------------------------------
// A2: edge extraction (+ conversion overlay blocks)
// ---------------------------------------------------------------------------
#define EDGE_WORK 800
__global__ __launch_bounds__(256) void edge_kernel(
    const float* __restrict__ adj, const float* __restrict__ MF,
    int* __restrict__ CNT, unsigned short* __restrict__ IDX,
    const float* cWq, const float* cWk, const float* cWv,
    const float* cWi, const float* cWo, unsigned short* OW,
    long long u0, long long u1)
{
    const int bid = blockIdx.x;
    if (bid >= EDGE_WORK) {
        conv_slice(cWq, cWk, cWv, cWi, cWo, OW, u0, u1,
                   (long long)(gridDim.x - EDGE_WORK) * 256,
                   (long long)(bid - EDGE_WORK) * 256 + threadIdx.x);
        return;
    }
    const int t = bid >> 4;
    const int r0 = (bid & 15) * 32;
    const int tid = threadIdx.x;

    __shared__ float mfS[NN];
    for (int j = tid; j < NN; j += 256) mfS[j] = MF[t * NN + j];
    __syncthreads();

    const int half = tid >> 7;
    const int l = tid & 127;

    for (int rr = 0; rr < 32; rr += 2) {
        const int i = r0 + rr + half;
        if (mfS[i] == 0.0f) continue;
        const float4 a4 = *reinterpret_cast<const float4*>(
            &adj[(size_t)t * NN * NN + (size_t)i * NN + l * 4]);
        const float av[4] = {a4.x, a4.y, a4.z, a4.w};
        const int jbase = l * 4;
#pragma unroll
        for (int u = 0; u < 4; ++u) {
            const int j = jbase + u;
            if (av[u] != 0.0f && mfS[j] != 0.0f) {
                int pos = atomicAdd(&CNT[t * NN + j], 1);
                if (pos < DEGCAP)   // 13-sigma headroom; dinv uses exact CNT
                    IDX[((size_t)t * NN + j) * DEGCAP + pos] = (unsigned short)i;
            }
        }
    }
}

__global__ __launch_bounds__(256) void dinv_kernel(
    const float* __restrict__ MF, const int* __restrict__ CNT,
    float* __restrict__ DINV)
{
    const int idx = blockIdx.x * 256 + threadIdx.x;
    DINV[idx] = (MF[idx] != 0.0f) ? rsqrtf((float)CNT[idx] + 1.0f) : 0.0f;
}

// ---------------------------------------------------------------------------
// B: XW1 = (x @ W1) * dinv -> bf16  (+ conversion overlay)
// ---------------------------------------------------------------------------
#define XW1_WORK 12800
__global__ __launch_bounds__(256) void xw1_kernel(
    const float* __restrict__ x, const float* __restrict__ W1,
    const float* __restrict__ DINV, unsigned short* __restrict__ XW16,
    const float* cWq, const float* cWk, const float* cWv,
    const float* cWi, const float* cWo, unsigned short* OW,
    long long u0, long long u1)
{
    const int bid = blockIdx.x;
    if (bid >= XW1_WORK) {
        conv_slice(cWq, cWk, cWv, cWi, cWo, OW, u0, u1,
                   (long long)(gridDim.x - XW1_WORK) * 256,
                   (long long)(bid - XW1_WORK) * 256 + threadIdx.x);
        return;
    }
    const int idx = bid * 256 + threadIdx.x;
    const int t = idx >> 16;
    const int r = idx & 65535;
    const int i = r >> 7;
    const int f = r & 127;
    const float* xp = x + ((size_t)t * NN + i) * DIN;
    float v = xp[0] * W1[f] + xp[1] * W1[HH + f] + xp[2] * W1[2 * HH + f];
    XW16[idx] = f2b(v * DINV[t * NN + i]);
}

// ---------------------------------------------------------------------------
// C: column aggregation (bf16 in/out, fp32 accum) (+ conversion overlay)
// ---------------------------------------------------------------------------
#define AGG_WORK (TT * NN)
__global__ __launch_bounds__(128) void agg_kernel(
    const unsigned short* __restrict__ XW16, const float* __restrict__ MF,
    const float* __restrict__ DINV, const int* __restrict__ CNT,
    const unsigned short* __restrict__ IDX, const float* __restrict__ bias,
    unsigned short* __restrict__ OUT16, int do_relu,
    const float* cWq, const float* cWk, const float* cWv,
    const float* cWi, const float* cWo, unsigned short* OW,
    long long u0, long long u1)
{
    const int bid = blockIdx.x;
    if (bid >= AGG_WORK) {
        conv_slice(cWq, cWk, cWv, cWi, cWo, OW, u0, u1,
                   (long long)(gridDim.x - AGG_WORK) * 128,
                   (long long)(bid - AGG_WORK) * 128 + threadIdx.x);
        return;
    }
    const int t = bid / NN;
    const int j = bid - t * NN;
    const int f = threadIdx.x;

    __shared__ unsigned short sidx[DEGCAP];

    const float mfj = MF[t * NN + j];
    int cnt = 0;
    if (mfj != 0.0f) cnt = min(CNT[t * NN + j], DEGCAP);
    const unsigned short* lst = IDX + ((size_t)t * NN + j) * DEGCAP;
    for (int k = f; k < cnt; k += 128) sidx[k] = lst[k];
    __syncthreads();

    float outv = 0.0f;
    if (mfj != 0.0f) {
        const unsigned short* base = XW16 + (size_t)t * NN * HH;
        float a0 = b2f(base[j * HH + f]), a1 = 0.0f, a2 = 0.0f, a3 = 0.0f;
        float a4 = 0.0f, a5 = 0.0f, a6 = 0.0f, a7 = 0.0f;
        int k = 0;
        for (; k + 8 <= cnt; k += 8) {
            a0 += b2f(base[(int)sidx[k]     * HH + f]);
            a1 += b2f(base[(int)sidx[k + 1] * HH + f]);
            a2 += b2f(base[(int)sidx[k + 2] * HH + f]);
            a3 += b2f(base[(int)sidx[k + 3] * HH + f]);
            a4 += b2f(base[(int)sidx[k + 4] * HH + f]);
            a5 += b2f(base[(int)sidx[k + 5] * HH + f]);
            a6 += b2f(base[(int)sidx[k + 6] * HH + f]);
            a7 += b2f(base[(int)sidx[k + 7] * HH + f]);
        }
        for (; k + 2 <= cnt; k += 2) {
            a0 += b2f(base[(int)sidx[k]     * HH + f]);
            a1 += b2f(base[(int)sidx[k + 1] * HH + f]);
        }
        if (k < cnt) a2 += b2f(base[(int)sidx[k] * HH + f]);
        outv = DINV[t * NN + j] * (((a0 + a1) + (a2 + a3)) + ((a4 + a5) + (a6 + a7))) + bias[f];
        if (do_relu) outv = fmaxf(outv, 0.0f);
    }
    OUT16[(size_t)t * NN * HH + j * HH + f] = f2b(outv);
}

// ---------------------------------------------------------------------------
// D (MFMA): XW2 = (H @ W2) * dinv (+ conversion overlay)
// ---------------------------------------------------------------------------
#define XW2_WORK 200
__global__ __launch_bounds__(256) void xw2_kernel(
    const unsigned short* __restrict__ H16, const float* __restrict__ W2,
    const float* __restrict__ DINV, unsigned short* __restrict__ XW16,
    const float* cWq, const float* cWk, const float* cWv,
    const float* cWi, const float* cWo, unsigned short* OW,
    long long u0, long long u1)
{
    __shared__ unsigned short sm[SMEM_X];
    const int bidx = blockIdx.x;
    if (bidx >= XW2_WORK) {
        conv_slice(cWq, cWk, cWv, cWi, cWo, OW, u0, u1,
                   (long long)(gridDim.x - XW2_WORK) * 256,
                   (long long)(bidx - XW2_WORK) * 256 + threadIdx.x);
        return;
    }
    const int r0 = bidx * 128;
    const int tid = threadIdx.x;
    const int lane = tid & 63;
    const int wid = tid >> 6;
    const int g = lane >> 4, c = lane & 15;
    const int nt0 = 2 * wid;

#pragma unroll
    for (int it = 0; it < 8; ++it) {
        const int idx = it * 256 + tid;
        const int row = idx >> 4, h8 = (idx & 15) * 8;
        *reinterpret_cast<short8*>(&sm[row * SROW + h8]) =
            *reinterpret_cast<const short8*>(&H16[(size_t)(r0 + row) * HH + h8]);
    }
#pragma unroll
    for (int it = 0; it < 16; ++it) {
        const int flat = it * 1024 + tid * 4;
        float4 w = *reinterpret_cast<const float4*>(W2 + flat);
        const int h = flat >> 7, f0 = flat & 127;
        sm[XW_WOFF + (f0 + 0) * SROW + h] = f2b(w.x);
        sm[XW_WOFF + (f0 + 1) * SROW + h] = f2b(w.y);
        sm[XW_WOFF + (f0 + 2) * SROW + h] = f2b(w.z);
        sm[XW_WOFF + (f0 + 3) * SROW + h] = f2b(w.w);
    }
    __syncthreads();

    f32x4 acc[8][2];
#pragma unroll
    for (int m = 0; m < 8; ++m)
#pragma unroll
        for (int i = 0; i < 2; ++i) acc[m][i] = (f32x4)(0.0f);

#pragma unroll
    for (int kb = 0; kb < 4; ++kb) {
        short8 bf[2];
#pragma unroll
        for (int i = 0; i < 2; ++i)
            bf[i] = *reinterpret_cast<const short8*>(
                &sm[XW_WOFF + (16 * (nt0 + i) + c) * SROW + kb * 32 + 8 * g]);
#pragma unroll
        for (int m = 0; m < 8; ++m) {
            short8 af = *reinterpret_cast<const short8*>(
                &sm[(16 * m + c) * SROW + kb * 32 + 8 * g]);
#pragma unroll
            for (int i = 0; i < 2; ++i)
                acc[m][i] = __builtin_amdgcn_mfma_f32_16x16x32_bf16(af, bf[i], acc[m][i], 0, 0, 0);
        }
    }

#pragma unroll
    for (int m = 0; m < 8; ++m)
#pragma unroll
        for (int r = 0; r < 4; ++r) {
            const int row = 16 * m + 4 * g + r;
            const float dv = DINV[r0 + row];
#pragma unroll
            for (int i = 0; i < 2; ++i)
                XW16[(size_t)(r0 + row) * HH + 16 * (nt0 + i) + c] = f2b(acc[m][i][r] * dv);
        }
}

// ---------------------------------------------------------------------------
// E1: per-(node,s) chained projection pair; B-frags read DIRECT from weights
// (fp32 or bf16 via load_bfrag). 512 thr / 8 waves, 1 col-tile per wave.
// ---------------------------------------------------------------------------
template<typename TW>
__global__ __launch_bounds__(512) void proj_kernel(
    const unsigned short* __restrict__ EMB16,
    const TW* __restrict__ Wq, const float* __restrict__ bq,
    const TW* __restrict__ Wk, const float* __restrict__ bk,
    const TW* __restrict__ Wv, const float* __restrict__ bv,
    const TW* __restrict__ Win, const float* __restrict__ b_in,
    unsigned short* __restrict__ QKVH)
{
    __shared__ unsigned short sm[SMEM_E1];
    const int bid = blockIdx.x;
    const int n = bid / 3;
    const int s = bid - 3 * n;
    const int tid = threadIdx.x;
    const int lane = tid & 63;
    const int wid = tid >> 6;
    const int g = lane >> 4, c = lane & 15;

    const size_t nHH = (size_t)n * HH * HH;
    const size_t n3HH = (size_t)n * 3 * HH * HH;

    const TW *Wa, *Wb;
    const float *ba, *bb;
    if (s == 0)      { Wa = Wq + nHH; ba = bq + (size_t)n * HH;
                       Wb = Win + n3HH;                 bb = b_in + (size_t)n * 3 * HH; }
    else if (s == 1) { Wa = Wk + nHH; ba = bk + (size_t)n * HH;
                       Wb = Win + n3HH + HH * HH;       bb = b_in + (size_t)n * 3 * HH + HH; }
    else             { Wa = Wv + nHH; ba = bv + (size_t)n * HH;
                       Wb = Win + n3HH + 2 * HH * HH;   bb = b_in + (size_t)n * 3 * HH + 2 * HH; }

    const int col = 16 * wid + c;
    const float bav = ba[col];
    const float bbv = bb[col];

    // stage emb (bf16) into bufA
    for (int idx = tid; idx < TT * (HH / 8); idx += 512) {
        int t = idx >> 4, h8 = (idx & 15) * 8;
        *reinterpret_cast<short8*>(&sm[t * SROW + h8]) =
            *reinterpret_cast<const short8*>(&EMB16[((size_t)t * NN + n) * HH + h8]);
    }
    __syncthreads();

    // GEMM1
    short8 bf[4];
#pragma unroll
    for (int kb = 0; kb < 4; ++kb) bf[kb] = load_bfrag(Wa, col, kb * 32 + 8 * g);
    f32x4 acc[4];
#pragma unroll
    for (int m = 0; m < 4; ++m) acc[m] = (f32x4)(0.0f);
#pragma unroll
    for (int kb = 0; kb < 4; ++kb) {
#pragma unroll
        for (int m = 0; m < 4; ++m) {
            short8 af = *reinterpret_cast<const short8*>(
                &sm[(16 * m + c) * SROW + kb * 32 + 8 * g]);
            acc[m] = __builtin_amdgcn_mfma_f32_16x16x32_bf16(af, bf[kb], acc[m], 0, 0, 0);
        }
    }
    __syncthreads();   // bufA-region reads done before bufB writes (regions overlap)

#pragma unroll
    for (int m = 0; m < 4; ++m)
#pragma unroll
        for (int r = 0; r < 4; ++r) {
            const int row = 16 * m + 4 * g + r;
            if (row >= TT) continue;
            sm[PB_OFF + row * SROW + col] = f2b(acc[m][r] + bav);
        }
    __syncthreads();

    // GEMM2
#pragma unroll
    for (int kb = 0; kb < 4; ++kb) bf[kb] = load_bfrag(Wb, col, kb * 32 + 8 * g);
#pragma unroll
    for (int m = 0; m < 4; ++m) acc[m] = (f32x4)(0.0f);
#pragma unroll
    for (int kb = 0; kb < 4; ++kb) {
#pragma unroll
        for (int m = 0; m < 4; ++m) {
            short8 af = *reinterpret_cast<const short8*>(
                &sm[PB_OFF + (16 * m + c) * SROW + kb * 32 + 8 * g]);
            acc[m] = __builtin_amdgcn_mfma_f32_16x16x32_bf16(af, bf[kb], acc[m], 0, 0, 0);
        }
    }

    constexpr float scale = 0.17677669529663687f;  // 1/sqrt(32)
    unsigned short* gout = QKVH + (size_t)(n * 3 + s) * (TT * HH);
#pragma unroll
    for (int m = 0; m < 4; ++m)
#pragma unroll
        for (int r = 0; r < 4; ++r) {
            const int row = 16 * m + 4 * g + r;
            if (row >= TT) continue;
            float v = acc[m][r] + bbv;
            if (s == 0) v *= scale;
            gout[row * HH + col] = f2b(v);
        }
}

// ---------------------------------------------------------------------------
// E2: per-node MHA + out_proj (wave = head); W_out fp32 or bf16.
// ---------------------------------------------------------------------------
template<typename TW>
__global__ __launch_bounds__(256) void attn_kernel(
    const unsigned short* __restrict__ QKVH,
    const TW* __restrict__ W_out, const float* __restrict__ b_out,
    float* __restrict__ out)
{
    __shared__ unsigned short sm[SMEM_E2];
    const int n = blockIdx.x;
    const int tid = threadIdx.x;
    const int lane = tid & 63;
    const int wid = tid >> 6;
    const int g = lane >> 4, c = lane & 15;
    const int nt0 = 2 * wid;

    // zero Svt tail (cols 50..55 each row + pad past row 127)
    for (int idx = tid; idx < HH * 6 + 16; idx += 256) {
        if (idx < HH * 6) {
            int d = idx / 6, cc = idx - d * 6;
            sm[SV_OFF + d * VROW + TT + cc] = 0;
        } else {
            sm[SV_OFF + HH * VROW + (idx - HH * 6)] = 0;
        }
    }

    const unsigned short* q16 = QKVH + (size_t)n * 3 * (TT * HH);
    for (int idx = tid; idx < TT * (HH / 8); idx += 256) {
        int t = idx >> 4, h8 = (idx & 15) * 8;
        *reinterpret_cast<short8*>(&sm[SQ_OFF + t * SROW + h8]) =
            *reinterpret_cast<const short8*>(&q16[t * HH + h8]);
        *reinterpret_cast<short8*>(&sm[SK_OFF + t * SROW + h8]) =
            *reinterpret_cast<const short8*>(&q16[TT * HH + t * HH + h8]);
    }
    for (int idx = tid; idx < TT * (HH / 8); idx += 256) {
        int t = idx >> 4, d8 = (idx & 15) * 8;
        short8 v = *reinterpret_cast<const short8*>(&q16[2 * TT * HH + t * HH + d8]);
#pragma unroll
        for (int u = 0; u < 8; ++u)
            sm[SV_OFF + (d8 + u) * VROW + t] = (unsigned short)v[u];
    }
    __syncthreads();

    const int hd = wid;

    f32x4 sacc[4][4];
#pragma unroll
    for (int m = 0; m < 4; ++m)
#pragma unroll
        for (int j = 0; j < 4; ++j) sacc[m][j] = (f32x4)(0.0f);

    short8 aq[4], bk8[4];
#pragma unroll
    for (int m = 0; m < 4; ++m)
        aq[m] = *reinterpret_cast<const short8*>(&sm[SQ_OFF + (16 * m + c) * SROW + hd * 32 + 8 * g]);
#pragma unroll
    for (int j = 0; j < 4; ++j)
        bk8[j] = *reinterpret_cast<const short8*>(&sm[SK_OFF + (16 * j + c) * SROW + hd * 32 + 8 * g]);
#pragma unroll
    for (int m = 0; m < 4; ++m)
#pragma unroll
        for (int j = 0; j < 4; ++j)
            sacc[m][j] = __builtin_amdgcn_mfma_f32_16x16x32_bf16(aq[m], bk8[j], sacc[m][j], 0, 0, 0);

    const bool mask3 = (c >= 2);
    unsigned short* Pbase = &sm[PQ_OFF + hd * 64 * PROW];
#pragma unroll
    for (int m = 0; m < 4; ++m)
#pragma unroll
        for (int r = 0; r < 4; ++r) {
            float v0 = sacc[m][0][r], v1 = sacc[m][1][r], v2 = sacc[m][2][r];
            float v3 = mask3 ? -3.0e38f : sacc[m][3][r];
            float mx = fmaxf(fmaxf(v0, v1), fmaxf(v2, v3));
            mx = fmaxf(mx, __shfl_xor(mx, 1, 16));
            mx = fmaxf(mx, __shfl_xor(mx, 2, 16));
            mx = fmaxf(mx, __shfl_xor(mx, 4, 16));
            mx = fmaxf(mx, __shfl_xor(mx, 8, 16));
            float e0 = __expf(v0 - mx), e1 = __expf(v1 - mx), e2 = __expf(v2 - mx);
            float e3 = mask3 ? 0.0f : __expf(v3 - mx);
            float sum_ = e0 + e1 + e2 + e3;
            sum_ += __shfl_xor(sum_, 1, 16);
            sum_ += __shfl_xor(sum_, 2, 16);
            sum_ += __shfl_xor(sum_, 4, 16);
            sum_ += __shfl_xor(sum_, 8, 16);
            float inv = 1.0f / sum_;
            const int q = 16 * m + 4 * g + r;
            unsigned short* pr = Pbase + q * PROW;
            pr[c]      = f2b(e0 * inv);
            pr[16 + c] = f2b(e1 * inv);
            pr[32 + c] = f2b(e2 * inv);
            pr[48 + c] = f2b(e3 * inv);
        }
    __syncthreads();

    f32x4 pacc[2][4];
#pragma unroll
    for (int mtd = 0; mtd < 2; ++mtd)
#pragma unroll
        for (int ntq = 0; ntq < 4; ++ntq) pacc[mtd][ntq] = (f32x4)(0.0f);

#pragma unroll
    for (int kb = 0; kb < 2; ++kb) {
        short8 av[2], bp[4];
#pragma unroll
        for (int mtd = 0; mtd < 2; ++mtd)
            av[mtd] = *reinterpret_cast<const short8*>(&sm[SV_OFF + (hd * 32 + 16 * mtd + c) * VROW + kb * 32 + 8 * g]);
#pragma unroll
        for (int ntq = 0; ntq < 4; ++ntq)
            bp[ntq] = *reinterpret_cast<const short8*>(&sm[PQ_OFF + hd * 64 * PROW + (16 * ntq + c) * PROW + kb * 32 + 8 * g]);
#pragma unroll
        for (int mtd = 0; mtd < 2; ++mtd)
#pragma unroll
            for (int ntq = 0; ntq < 4; ++ntq)
                pacc[mtd][ntq] = __builtin_amdgcn_mfma_f32_16x16x32_bf16(av[mtd], bp[ntq], pacc[mtd][ntq], 0, 0, 0);
    }

#pragma unroll
    for (int mtd = 0; mtd < 2; ++mtd)
#pragma unroll
        for (int ntq = 0; ntq < 4; ++ntq)
#pragma unroll
            for (int r = 0; r < 4; ++r) {
                const int q = 16 * ntq + c;
                if (q < TT)
                    sm[SQ_OFF + q * SROW + hd * 32 + 16 * mtd + 4 * g + r] = f2b(pacc[mtd][ntq][r]);
            }
    __syncthreads();

    // out_proj with typed weight loader
    const TW* Wo = W_out + (size_t)n * HH * HH;
    short8 bfO[2][4];
#pragma unroll
    for (int i = 0; i < 2; ++i)
#pragma unroll
        for (int kb = 0; kb < 4; ++kb)
            bfO[i][kb] = load_bfrag(Wo, 16 * (nt0 + i) + c, kb * 32 + 8 * g);

    f32x4 acc[4][2];
#pragma unroll
    for (int m = 0; m < 4; ++m)
#pragma unroll
        for (int i = 0; i < 2; ++i) acc[m][i] = (f32x4)(0.0f);
#pragma unroll
    for (int kb = 0; kb < 4; ++kb) {
        short8 af[4];
#pragma unroll
        for (int m = 0; m < 4; ++m)
            af[m] = *reinterpret_cast<const short8*>(&sm[SQ_OFF + (16 * m + c) * SROW + kb * 32 + 8 * g]);
#pragma unroll
        for (int m = 0; m < 4; ++m)
#pragma unroll
            for (int i = 0; i < 2; ++i)
                acc[m][i] = __builtin_amdgcn_mfma_f32_16x16x32_bf16(af[m], bfO[i][kb], acc[m][i], 0, 0, 0);
    }

    const float bo0 = b_out[(size_t)n * HH + 16 * nt0 + c];
    const float bo1 = b_out[(size_t)n * HH + 16 * nt0 + 16 + c];
    float* outp = out + (size_t)n * (TT * HH);
#pragma unroll
    for (int m = 0; m < 4; ++m)
#pragma unroll
        for (int i = 0; i < 2; ++i)
#pragma unroll
            for (int r = 0; r < 4; ++r) {
                const int row = 16 * m + 4 * g + r;
                if (row >= TT) continue;
                outp[row * HH + 16 * (nt0 + i) + c] = acc[m][i][r] + (i ? bo1 : bo0);
            }
}

// ---------------------------------------------------------------------------
extern "C" void kernel_launch(void* const* d_in, const int* in_sizes, int n_in,
                              void* d_out, int out_size, void* d_ws, size_t ws_size,
                              hipStream_t stream)
{
    const float* x     = (const float*)d_in[0];
    const float* adj   = (const float*)d_in[1];
    const int*   ego   = (const int*)d_in[2];
    const float* W1    = (const float*)d_in[3];
    const float* b1    = (const float*)d_in[4];
    const float* W2    = (const float*)d_in[5];
    const float* b2    = (const float*)d_in[6];
    const float* Wq    = (const float*)d_in[7];
    const float* bq    = (const float*)d_in[8];
    const float* Wk    = (const float*)d_in[9];
    const float* bk    = (const float*)d_in[10];
    const float* Wv    = (const float*)d_in[11];
    const float* bv    = (const float*)d_in[12];
    const float* W_in  = (const float*)d_in[13];
    const float* b_in  = (const float*)d_in[14];
    const float* W_out = (const float*)d_in[15];
    const float* b_out = (const float*)d_in[16];
    float* out = (float*)d_out;

    char* ws = (char*)d_ws;
    float*          MF    = (float*)(ws + 0);
    float*          DINV  = (float*)(ws + 102400);
    int*            CNT   = (int*)(ws + 204800);
    unsigned short* IDX   = (unsigned short*)(ws + 307200);     // T*NN*128*2 = 6,553,600
    unsigned short* XW16  = (unsigned short*)(ws + 6860800);    // 6,553,600
    unsigned short* H16   = (unsigned short*)(ws + 13414400);   // 6,553,600
    unsigned short* EMB16 = (unsigned short*)(ws + 19968000);   // 6,553,600
    unsigned short* QKVH  = (unsigned short*)(ws + 26521600);   // 19,660,800
    unsigned short* OW    = (unsigned short*)(ws + 46182400);   // 117,440,512 bf16 weights

    const bool bigws = ws_size >= 46182400ull + 117440512ull;
    unsigned short* OWp = bigws ? OW : (unsigned short*)nullptr;

    // conversion slices (float4 units over {Wq,Wk,Wv,W_in,W_out} = 14,680,064)
    const long long UT = 14680064LL;
    const long long c1 = UT * 30 / 100, c2 = UT * 45 / 100,
                    c3 = UT * 65 / 100, c4 = UT * 75 / 100;
    const int ceb = bigws ? 1024 : 0, cx1 = bigws ? 1024 : 0, ca1 = bigws ? 1024 : 0,
              cx2 = bigws ? 512 : 0,  ca2 = bigws ? 1024 : 0;

    hipMemsetAsync(CNT, 0, TT * NN * sizeof(int), stream);
    mf_kernel<<<dim3(100), dim3(256), 0, stream>>>(ego, MF);
    edge_kernel<<<dim3(EDGE_WORK + ceb), dim3(256), 0, stream>>>(
        adj, MF, CNT, IDX, Wq, Wk, Wv, W_in, W_out, OWp, 0, bigws ? c1 : 0);
    dinv_kernel<<<dim3(100), dim3(256), 0, stream>>>(MF, CNT, DINV);
    xw1_kernel<<<dim3(XW1_WORK + cx1), dim3(256), 0, stream>>>(
        x, W1, DINV, XW16, Wq, Wk, Wv, W_in, W_out, OWp, c1, bigws ? c2 : c1);
    agg_kernel<<<dim3(AGG_WORK + ca1), dim3(128), 0, stream>>>(
        XW16, MF, DINV, CNT, IDX, b1, H16, 1, Wq, Wk, Wv, W_in, W_out, OWp, c2, bigws ? c3 : c2);
    xw2_kernel<<<dim3(XW2_WORK + cx2), dim3(256), 0, stream>>>(
        H16, W2, DINV, XW16, Wq, Wk, Wv, W_in, W_out, OWp, c3, bigws ? c4 : c3);
    agg_kernel<<<dim3(AGG_WORK + ca2), dim3(128), 0, stream>>>(
        XW16, MF, DINV, CNT, IDX, b2, EMB16, 0, Wq, Wk, Wv, W_in, W_out, OWp, c4, bigws ? UT : c4);

    if (bigws) {
        proj_kernel<unsigned short><<<dim3(NN * 3), dim3(512), 0, stream>>>(
            EMB16, OW, bq, OW + 8388608, bk, OW + 16777216, bv, OW + 25165824, b_in, QKVH);
        attn_kernel<unsigned short><<<dim3(NN), dim3(256), 0, stream>>>(
            QKVH, OW + 50331648, b_out, out);
    } else {
        proj_kernel<float><<<dim3(NN * 3), dim3(512), 0, stream>>>(
            EMB16, Wq, bq, Wk, bk, Wv, bv, W_in, b_in, QKVH);
        attn_kernel<float><<<dim3(NN), dim3(256), 0, stream>>>(
            QKVH, W_out, b_out, out);
    }
}

// Round 11
// 174.656 us; speedup vs baseline: 1.2854x; 1.2854x over previous
//
#include <hip/hip_runtime.h>
#include <hip/hip_bf16.h>
#include <cstddef>

#define TT 50
#define NN 512
#define DIN 3
#define HH 128
#define NPG 64
#define DEGCAP 128

typedef short short8 __attribute__((ext_vector_type(8)));
typedef float f32x4 __attribute__((ext_vector_type(4)));

// ---- LDS strides (ushort elems) ----
#define SROW 136
#define VROW 56
#define PROW 72
// attn layout
#define SQ_OFF 0
#define SK_OFF 6800
#define SV_OFF 13600
#define PQ_OFF 20784
#define SMEM_E2 39216      // 78,432 B -> 2 blocks/CU
// proj layout: bufA @0, bufB @6800 (A-frag rows 50..63 overread bufB: discarded)
#define PB_OFF 6800
#define SMEM_E1 15504      // 31,008 B
// xw2 layout
#define XW_WOFF 17408
#define SMEM_X 34816

static __device__ __forceinline__ unsigned short f2b(float f) {
    unsigned int u = __builtin_bit_cast(unsigned int, f);
    unsigned int r = (u + 0x7fffu + ((u >> 16) & 1u)) >> 16;
    return (unsigned short)r;
}
static __device__ __forceinline__ float b2f(unsigned short h) {
    unsigned int u = ((unsigned int)h) << 16;
    return __builtin_bit_cast(float, u);
}

// Barrier that does NOT drain vmcnt (LDS-only visibility).
static __device__ __forceinline__ void block_sync() {
    __builtin_amdgcn_sched_barrier(0);
    asm volatile("s_waitcnt lgkmcnt(0)");
    __builtin_amdgcn_s_barrier();
    __builtin_amdgcn_sched_barrier(0);
}
static __device__ __forceinline__ void wait_vm0() {
    asm volatile("s_waitcnt vmcnt(0)" ::: "memory");
    __builtin_amdgcn_sched_barrier(0);
}

// asm-pinned 8x global_load_dwordx4 of one 16-row weight tile slice (cannot
// be sunk by the scheduler; stays in flight until wait_vm0).
__device__ __forceinline__ void issue_w8(const float* __restrict__ base8,
                                         float4 (&wr)[16], int off)
{
#pragma unroll
    for (int kb = 0; kb < 4; ++kb) {
        asm volatile("global_load_dwordx4 %0, %1, off"
                     : "=&v"(wr[off + kb * 2]) : "v"(base8 + kb * 32));
        asm volatile("global_load_dwordx4 %0, %1, off offset:16"
                     : "=&v"(wr[off + kb * 2 + 1]) : "v"(base8 + kb * 32));
    }
}
__device__ __forceinline__ void conv8(const float4 (&wr)[16], int off, short8 (&bf)[4]) {
#pragma unroll
    for (int kb = 0; kb < 4; ++kb) {
        float4 w0 = wr[off + kb * 2];
        float4 w1 = wr[off + kb * 2 + 1];
        short8 t;
        t[0] = (short)f2b(w0.x); t[1] = (short)f2b(w0.y);
        t[2] = (short)f2b(w0.z); t[3] = (short)f2b(w0.w);
        t[4] = (short)f2b(w1.x); t[5] = (short)f2b(w1.y);
        t[6] = (short)f2b(w1.z); t[7] = (short)f2b(w1.w);
        bf[kb] = t;
    }
}

// ---------------------------------------------------------------------------
// A0: ego mask -> MF
// ---------------------------------------------------------------------------
__global__ __launch_bounds__(256) void mf_kernel(
    const int* __restrict__ ego, float* __restrict__ MF)
{
    const int idx = blockIdx.x * 256 + threadIdx.x;
    const int t = idx >> 9;
    const int i = idx & 511;
    const int b = i >> 6, p = i & 63;
    MF[idx] = (ego[b * (TT * NPG) + t * NPG + p] != 0) ? 1.0f : 0.0f;
}

// ---------------------------------------------------------------------------
// A2: edge extraction (row scan + atomic scatter, capped lists)
// ---------------------------------------------------------------------------
__global__ __launch_bounds__(256) void edge_kernel(
    const float* __restrict__ adj, const float* __restrict__ MF,
    int* __restrict__ CNT, unsigned short* __restrict__ IDX)
{
    const int bid = blockIdx.x;        // t*16 + chunk
    const int t = bid >> 4;
    const int r0 = (bid & 15) * 32;
    const int tid = threadIdx.x;

    __shared__ float mfS[NN];
    for (int j = tid; j < NN; j += 256) mfS[j] = MF[t * NN + j];
    __syncthreads();

    const int half = tid >> 7;
    const int l = tid & 127;

    for (int rr = 0; rr < 32; rr += 2) {
        const int i = r0 + rr + half;
        if (mfS[i] == 0.0f) continue;
        const float4 a4 = *reinterpret_cast<const float4*>(
            &adj[(size_t)t * NN * NN + (size_t)i * NN + l * 4]);
        const float av[4] = {a4.x, a4.y, a4.z, a4.w};
        const int jbase = l * 4;
#pragma unroll
        for (int u = 0; u < 4; ++u) {
            const int j = jbase + u;
            if (av[u] != 0.0f && mfS[j] != 0.0f) {
                int pos = atomicAdd(&CNT[t * NN + j], 1);
                if (pos < DEGCAP)   // 13-sigma headroom; dinv uses exact CNT
                    IDX[((size_t)t * NN + j) * DEGCAP + pos] = (unsigned short)i;
            }
        }
    }
}

__global__ __launch_bounds__(256) void dinv_kernel(
    const float* __restrict__ MF, const int* __restrict__ CNT,
    float* __restrict__ DINV)
{
    const int idx = blockIdx.x * 256 + threadIdx.x;
    DINV[idx] = (MF[idx] != 0.0f) ? rsqrtf((float)CNT[idx] + 1.0f) : 0.0f;
}

// ---------------------------------------------------------------------------
// B: XW1 = (x @ W1) * dinv -> bf16
// ---------------------------------------------------------------------------
__global__ __launch_bounds__(256) void xw1_kernel(
    const float* __restrict__ x, const float* __restrict__ W1,
    const float* __restrict__ DINV, unsigned short* __restrict__ XW16)
{
    const int idx = blockIdx.x * 256 + threadIdx.x;
    const int t = idx >> 16;
    const int r = idx & 65535;
    const int i = r >> 7;
    const int f = r & 127;
    const float* xp = x + ((size_t)t * NN + i) * DIN;
    float v = xp[0] * W1[f] + xp[1] * W1[HH + f] + xp[2] * W1[2 * HH + f];
    XW16[idx] = f2b(v * DINV[t * NN + i]);
}

// ---------------------------------------------------------------------------
// C: column aggregation (bf16 in/out, fp32 accum)
// ---------------------------------------------------------------------------
__global__ __launch_bounds__(128) void agg_kernel(
    const unsigned short* __restrict__ XW16, const float* __restrict__ MF,
    const float* __restrict__ DINV, const int* __restrict__ CNT,
    const unsigned short* __restrict__ IDX, const float* __restrict__ bias,
    unsigned short* __restrict__ OUT16, int do_relu)
{
    const int bid = blockIdx.x;
    const int t = bid / NN;
    const int j = bid - t * NN;
    const int f = threadIdx.x;

    __shared__ unsigned short sidx[DEGCAP];

    const float mfj = MF[t * NN + j];
    int cnt = 0;
    if (mfj != 0.0f) cnt = min(CNT[t * NN + j], DEGCAP);
    const unsigned short* lst = IDX + ((size_t)t * NN + j) * DEGCAP;
    for (int k = f; k < cnt; k += 128) sidx[k] = lst[k];
    __syncthreads();

    float outv = 0.0f;
    if (mfj != 0.0f) {
        const unsigned short* base = XW16 + (size_t)t * NN * HH;
        float a0 = b2f(base[j * HH + f]), a1 = 0.0f, a2 = 0.0f, a3 = 0.0f;
        float a4 = 0.0f, a5 = 0.0f, a6 = 0.0f, a7 = 0.0f;
        int k = 0;
        for (; k + 8 <= cnt; k += 8) {
            a0 += b2f(base[(int)sidx[k]     * HH + f]);
            a1 += b2f(base[(int)sidx[k + 1] * HH + f]);
            a2 += b2f(base[(int)sidx[k + 2] * HH + f]);
            a3 += b2f(base[(int)sidx[k + 3] * HH + f]);
            a4 += b2f(base[(int)sidx[k + 4] * HH + f]);
            a5 += b2f(base[(int)sidx[k + 5] * HH + f]);
            a6 += b2f(base[(int)sidx[k + 6] * HH + f]);
            a7 += b2f(base[(int)sidx[k + 7] * HH + f]);
        }
        for (; k + 2 <= cnt; k += 2) {
            a0 += b2f(base[(int)sidx[k]     * HH + f]);
            a1 += b2f(base[(int)sidx[k + 1] * HH + f]);
        }
        if (k < cnt) a2 += b2f(base[(int)sidx[k] * HH + f]);
        outv = DINV[t * NN + j] * (((a0 + a1) + (a2 + a3)) + ((a4 + a5) + (a6 + a7))) + bias[f];
        if (do_relu) outv = fmaxf(outv, 0.0f);
    }
    OUT16[(size_t)t * NN * HH + j * HH + f] = f2b(outv);
}

// ---------------------------------------------------------------------------
// D (MFMA): XW2 = (H @ W2) * dinv on flat [25600][128]
// ---------------------------------------------------------------------------
__global__ __launch_bounds__(256) void xw2_kernel(
    const unsigned short* __restrict__ H16, const float* __restrict__ W2,
    const float* __restrict__ DINV, unsigned short* __restrict__ XW16)
{
    __shared__ unsigned short sm[SMEM_X];
    const int r0 = blockIdx.x * 128;
    const int tid = threadIdx.x;
    const int lane = tid & 63;
    const int wid = tid >> 6;
    const int g = lane >> 4, c = lane & 15;
    const int nt0 = 2 * wid;

#pragma unroll
    for (int it = 0; it < 8; ++it) {
        const int idx = it * 256 + tid;
        const int row = idx >> 4, h8 = (idx & 15) * 8;
        *reinterpret_cast<short8*>(&sm[row * SROW + h8]) =
            *reinterpret_cast<const short8*>(&H16[(size_t)(r0 + row) * HH + h8]);
    }
#pragma unroll
    for (int it = 0; it < 16; ++it) {
        const int flat = it * 1024 + tid * 4;
        float4 w = *reinterpret_cast<const float4*>(W2 + flat);
        const int h = flat >> 7, f0 = flat & 127;
        sm[XW_WOFF + (f0 + 0) * SROW + h] = f2b(w.x);
        sm[XW_WOFF + (f0 + 1) * SROW + h] = f2b(w.y);
        sm[XW_WOFF + (f0 + 2) * SROW + h] = f2b(w.z);
        sm[XW_WOFF + (f0 + 3) * SROW + h] = f2b(w.w);
    }
    __syncthreads();

    f32x4 acc[8][2];
#pragma unroll
    for (int m = 0; m < 8; ++m)
#pragma unroll
        for (int i = 0; i < 2; ++i) acc[m][i] = (f32x4)(0.0f);

#pragma unroll
    for (int kb = 0; kb < 4; ++kb) {
        short8 bf[2];
#pragma unroll
        for (int i = 0; i < 2; ++i)
            bf[i] = *reinterpret_cast<const short8*>(
                &sm[XW_WOFF + (16 * (nt0 + i) + c) * SROW + kb * 32 + 8 * g]);
#pragma unroll
        for (int m = 0; m < 8; ++m) {
            short8 af = *reinterpret_cast<const short8*>(
                &sm[(16 * m + c) * SROW + kb * 32 + 8 * g]);
#pragma unroll
            for (int i = 0; i < 2; ++i)
                acc[m][i] = __builtin_amdgcn_mfma_f32_16x16x32_bf16(af, bf[i], acc[m][i], 0, 0, 0);
        }
    }

#pragma unroll
    for (int m = 0; m < 8; ++m)
#pragma unroll
        for (int r = 0; r < 4; ++r) {
            const int row = 16 * m + 4 * g + r;
            const float dv = DINV[r0 + row];
#pragma unroll
            for (int i = 0; i < 2; ++i)
                XW16[(size_t)(r0 + row) * HH + 16 * (nt0 + i) + c] = f2b(acc[m][i][r] * dv);
        }
}

// ---------------------------------------------------------------------------
// E1: per-(node,s) chained projection pair. MLP experiment: ALL 16 weight
// loads (GEMM1 + GEMM2 tiles) issued in one asm-pinned burst up-front,
// overlapped with emb staging; single vmcnt stall per kernel.
// 512 thr / 8 waves, 1 col-tile per wave.
// ---------------------------------------------------------------------------
__global__ __launch_bounds__(512) void proj_kernel(
    const unsigned short* __restrict__ EMB16,
    const float* __restrict__ Wq, const float* __restrict__ bq,
    const float* __restrict__ Wk, const float* __restrict__ bk,
    const float* __restrict__ Wv, const float* __restrict__ bv,
    const float* __restrict__ Win, const float* __restrict__ b_in,
    unsigned short* __restrict__ QKVH)
{
    __shared__ unsigned short sm[SMEM_E1];
    const int bid = blockIdx.x;
    const int n = bid / 3;
    const int s = bid - 3 * n;
    const int tid = threadIdx.x;
    const int lane = tid & 63;
    const int wid = tid >> 6;
    const int g = lane >> 4, c = lane & 15;

    const size_t nHH = (size_t)n * HH * HH;
    const size_t n3HH = (size_t)n * 3 * HH * HH;

    const float *Wa, *Wb, *ba, *bb;
    if (s == 0)      { Wa = Wq + nHH; ba = bq + (size_t)n * HH;
                       Wb = Win + n3HH;                 bb = b_in + (size_t)n * 3 * HH; }
    else if (s == 1) { Wa = Wk + nHH; ba = bk + (size_t)n * HH;
                       Wb = Win + n3HH + HH * HH;       bb = b_in + (size_t)n * 3 * HH + HH; }
    else             { Wa = Wv + nHH; ba = bv + (size_t)n * HH;
                       Wb = Win + n3HH + 2 * HH * HH;   bb = b_in + (size_t)n * 3 * HH + 2 * HH; }

    const int col = 16 * wid + c;

    // --- issue ALL weight loads up-front (16 dwordx4 in flight per lane) ---
    float4 wr[16];
    issue_w8(Wa + col * HH + 8 * g, wr, 0);
    issue_w8(Wb + col * HH + 8 * g, wr, 8);

    const float bav = ba[col];
    const float bbv = bb[col];

    // stage emb (bf16) into bufA while weight loads fly
    for (int idx = tid; idx < TT * (HH / 8); idx += 512) {
        int t = idx >> 4, h8 = (idx & 15) * 8;
        *reinterpret_cast<short8*>(&sm[t * SROW + h8]) =
            *reinterpret_cast<const short8*>(&EMB16[((size_t)t * NN + n) * HH + h8]);
    }
    block_sync();              // LDS visible; weight loads STILL in flight

    wait_vm0();                // the single weight-stream stall
    short8 bfA[4], bfB[4];
    conv8(wr, 0, bfA);
    conv8(wr, 8, bfB);

    // GEMM1
    f32x4 acc[4];
#pragma unroll
    for (int m = 0; m < 4; ++m) acc[m] = (f32x4)(0.0f);
#pragma unroll
    for (int kb = 0; kb < 4; ++kb) {
#pragma unroll
        for (int m = 0; m < 4; ++m) {
            short8 af = *reinterpret_cast<const short8*>(
                &sm[(16 * m + c) * SROW + kb * 32 + 8 * g]);
            acc[m] = __builtin_amdgcn_mfma_f32_16x16x32_bf16(af, bfA[kb], acc[m], 0, 0, 0);
        }
    }
    block_sync();   // bufA-region reads done before bufB writes (regions overlap)

#pragma unroll
    for (int m = 0; m < 4; ++m)
#pragma unroll
        for (int r = 0; r < 4; ++r) {
            const int row = 16 * m + 4 * g + r;
            if (row >= TT) continue;
            sm[PB_OFF + row * SROW + col] = f2b(acc[m][r] + bav);
        }
    block_sync();

    // GEMM2 (weights already in registers)
#pragma unroll
    for (int m = 0; m < 4; ++m) acc[m] = (f32x4)(0.0f);
#pragma unroll
    for (int kb = 0; kb < 4; ++kb) {
#pragma unroll
        for (int m = 0; m < 4; ++m) {
            short8 af = *reinterpret_cast<const short8*>(
                &sm[PB_OFF + (16 * m + c) * SROW + kb * 32 + 8 * g]);
            acc[m] = __builtin_amdgcn_mfma_f32_16x16x32_bf16(af, bfB[kb], acc[m], 0, 0, 0);
        }
    }

    constexpr float scale = 0.17677669529663687f;  // 1/sqrt(32)
    unsigned short* gout = QKVH + (size_t)(n * 3 + s) * (TT * HH);
#pragma unroll
    for (int m = 0; m < 4; ++m)
#pragma unroll
        for (int r = 0; r < 4; ++r) {
            const int row = 16 * m + 4 * g + r;
            if (row >= TT) continue;
            float v = acc[m][r] + bbv;
            if (s == 0) v *= scale;
            gout[row * HH + col] = f2b(v);
        }
}

// ---------------------------------------------------------------------------
// E2: per-node MHA + out_proj (wave = head). W_out loads asm-burst at start,
// consumed after attention (R5-proven pattern).
// ---------------------------------------------------------------------------
__global__ __launch_bounds__(256) void attn_kernel(
    const unsigned short* __restrict__ QKVH,
    const float* __restrict__ W_out, const float* __restrict__ b_out,
    float* __restrict__ out)
{
    __shared__ unsigned short sm[SMEM_E2];
    const int n = blockIdx.x;
    const int tid = threadIdx.x;
    const int lane = tid & 63;
    const int wid = tid >> 6;
    const int g = lane >> 4, c = lane & 15;
    const int nt0 = 2 * wid;

    // issue W_out loads up-front (2 tiles/wave = 16 loads), fly across attention
    float4 wr[16];
    const float* Wo = W_out + (size_t)n * HH * HH;
    issue_w8(Wo + (16 * nt0 + c) * HH + 8 * g, wr, 0);
    issue_w8(Wo + (16 * nt0 + 16 + c) * HH + 8 * g, wr, 8);

    // zero Svt tail (cols 50..55 each row + pad past row 127)
    for (int idx = tid; idx < HH * 6 + 16; idx += 256) {
        if (idx < HH * 6) {
            int d = idx / 6, cc = idx - d * 6;
            sm[SV_OFF + d * VROW + TT + cc] = 0;
        } else {
            sm[SV_OFF + HH * VROW + (idx - HH * 6)] = 0;
        }
    }

    const unsigned short* q16 = QKVH + (size_t)n * 3 * (TT * HH);
    for (int idx = tid; idx < TT * (HH / 8); idx += 256) {
        int t = idx >> 4, h8 = (idx & 15) * 8;
        *reinterpret_cast<short8*>(&sm[SQ_OFF + t * SROW + h8]) =
            *reinterpret_cast<const short8*>(&q16[t * HH + h8]);
        *reinterpret_cast<short8*>(&sm[SK_OFF + t * SROW + h8]) =
            *reinterpret_cast<const short8*>(&q16[TT * HH + t * HH + h8]);
    }
    for (int idx = tid; idx < TT * (HH / 8); idx += 256) {
        int t = idx >> 4, d8 = (idx & 15) * 8;
        short8 v = *reinterpret_cast<const short8*>(&q16[2 * TT * HH + t * HH + d8]);
#pragma unroll
        for (int u = 0; u < 8; ++u)
            sm[SV_OFF + (d8 + u) * VROW + t] = (unsigned short)v[u];
    }
    block_sync();

    const int hd = wid;

    f32x4 sacc[4][4];
#pragma unroll
    for (int m = 0; m < 4; ++m)
#pragma unroll
        for (int j = 0; j < 4; ++j) sacc[m][j] = (f32x4)(0.0f);

    short8 aq[4], bk8[4];
#pragma unroll
    for (int m = 0; m < 4; ++m)
        aq[m] = *reinterpret_cast<const short8*>(&sm[SQ_OFF + (16 * m + c) * SROW + hd * 32 + 8 * g]);
#pragma unroll
    for (int j = 0; j < 4; ++j)
        bk8[j] = *reinterpret_cast<const short8*>(&sm[SK_OFF + (16 * j + c) * SROW + hd * 32 + 8 * g]);
#pragma unroll
    for (int m = 0; m < 4; ++m)
#pragma unroll
        for (int j = 0; j < 4; ++j)
            sacc[m][j] = __builtin_amdgcn_mfma_f32_16x16x32_bf16(aq[m], bk8[j], sacc[m][j], 0, 0, 0);

    const bool mask3 = (c >= 2);
    unsigned short* Pbase = &sm[PQ_OFF + hd * 64 * PROW];
#pragma unroll
    for (int m = 0; m < 4; ++m)
#pragma unroll
        for (int r = 0; r < 4; ++r) {
            float v0 = sacc[m][0][r], v1 = sacc[m][1][r], v2 = sacc[m][2][r];
            float v3 = mask3 ? -3.0e38f : sacc[m][3][r];
            float mx = fmaxf(fmaxf(v0, v1), fmaxf(v2, v3));
            mx = fmaxf(mx, __shfl_xor(mx, 1, 16));
            mx = fmaxf(mx, __shfl_xor(mx, 2, 16));
            mx = fmaxf(mx, __shfl_xor(mx, 4, 16));
            mx = fmaxf(mx, __shfl_xor(mx, 8, 16));
            float e0 = __expf(v0 - mx), e1 = __expf(v1 - mx), e2 = __expf(v2 - mx);
            float e3 = mask3 ? 0.0f : __expf(v3 - mx);
            float sum_ = e0 + e1 + e2 + e3;
            sum_ += __shfl_xor(sum_, 1, 16);
            sum_ += __shfl_xor(sum_, 2, 16);
            sum_ += __shfl_xor(sum_, 4, 16);
            sum_ += __shfl_xor(sum_, 8, 16);
            float inv = 1.0f / sum_;
            const int q = 16 * m + 4 * g + r;
            unsigned short* pr = Pbase + q * PROW;
            pr[c]      = f2b(e0 * inv);
            pr[16 + c] = f2b(e1 * inv);
            pr[32 + c] = f2b(e2 * inv);
            pr[48 + c] = f2b(e3 * inv);
        }
    block_sync();

    f32x4 pacc[2][4];
#pragma unroll
    for (int mtd = 0; mtd < 2; ++mtd)
#pragma unroll
        for (int ntq = 0; ntq < 4; ++ntq) pacc[mtd][ntq] = (f32x4)(0.0f);

#pragma unroll
    for (int kb = 0; kb < 2; ++kb) {
        short8 av[2], bp[4];
#pragma unroll
        for (int mtd = 0; mtd < 2; ++mtd)
            av[mtd] = *reinterpret_cast<const short8*>(&sm[SV_OFF + (hd * 32 + 16 * mtd + c) * VROW + kb * 32 + 8 * g]);
#pragma unroll
        for (int ntq = 0; ntq < 4; ++ntq)
            bp[ntq] = *reinterpret_cast<const short8*>(&sm[PQ_OFF + hd * 64 * PROW + (16 * ntq + c) * PROW + kb * 32 + 8 * g]);
#pragma unroll
        for (int mtd = 0; mtd < 2; ++mtd)
#pragma unroll
            for (int ntq = 0; ntq < 4; ++ntq)
                pacc[mtd][ntq] = __builtin_amdgcn_mfma_f32_16x16x32_bf16(av[mtd], bp[ntq], pacc[mtd][ntq], 0, 0, 0);
    }

#pragma unroll
    for (int mtd = 0; mtd < 2; ++mtd)
#pragma unroll
        for (int ntq = 0; ntq < 4; ++ntq)
#pragma unroll
            for (int r = 0; r < 4; ++r) {
                const int q = 16 * ntq + c;
                if (q < TT)
                    sm[SQ_OFF + q * SROW + hd * 32 + 16 * mtd + 4 * g + r] = f2b(pacc[mtd][ntq][r]);
            }
    block_sync();

    // out_proj: weights have been in flight across the whole attention section
    wait_vm0();
    short8 bfO[2][4];
    conv8(wr, 0, bfO[0]);
    conv8(wr, 8, bfO[1]);

    f32x4 acc[4][2];
#pragma unroll
    for (int m = 0; m < 4; ++m)
#pragma unroll
        for (int i = 0; i < 2; ++i) acc[m][i] = (f32x4)(0.0f);
#pragma unroll
    for (int kb = 0; kb < 4; ++kb) {
        short8 af[4];
#pragma unroll
        for (int m = 0; m < 4; ++m)
            af[m] = *reinterpret_cast<const short8*>(&sm[SQ_OFF + (16 * m + c) * SROW + kb * 32 + 8 * g]);
#pragma unroll
        for (int m = 0; m < 4; ++m)
#pragma unroll
            for (int i = 0; i < 2; ++i)
                acc[m][i] = __builtin_amdgcn_mfma_f32_16x16x32_bf16(af[m], bfO[i][kb], acc[m][i], 0, 0, 0);
    }

    const float bo0 = b_out[(size_t)n * HH + 16 * nt0 + c];
    const float bo1 = b_out[(size_t)n * HH + 16 * nt0 + 16 + c];
    float* outp = out + (size_t)n * (TT * HH);
#pragma unroll
    for (int m = 0; m < 4; ++m)
#pragma unroll
        for (int i = 0; i < 2; ++i)
#pragma unroll
            for (int r = 0; r < 4; ++r) {
                const int row = 16 * m + 4 * g + r;
                if (row >= TT) continue;
                outp[row * HH + 16 * (nt0 + i) + c] = acc[m][i][r] + (i ? bo1 : bo0);
            }
}

// ---------------------------------------------------------------------------
extern "C" void kernel_launch(void* const* d_in, const int* in_sizes, int n_in,
                              void* d_out, int out_size, void* d_ws, size_t ws_size,
                              hipStream_t stream)
{
    const float* x     = (const float*)d_in[0];
    const float* adj   = (const float*)d_in[1];
    const int*   ego   = (const int*)d_in[2];
    const float* W1    = (const float*)d_in[3];
    const float* b1    = (const float*)d_in[4];
    const float* W2    = (const float*)d_in[5];
    const float* b2    = (const float*)d_in[6];
    const float* Wq    = (const float*)d_in[7];
    const float* bq    = (const float*)d_in[8];
    const float* Wk    = (const float*)d_in[9];
    const float* bk    = (const float*)d_in[10];
    const float* Wv    = (const float*)d_in[11];
    const float* bv    = (const float*)d_in[12];
    const float* W_in  = (const float*)d_in[13];
    const float* b_in  = (const float*)d_in[14];
    const float* W_out = (const float*)d_in[15];
    const float* b_out = (const float*)d_in[16];
    float* out = (float*)d_out;

    char* ws = (char*)d_ws;
    float*          MF    = (float*)(ws + 0);
    float*          DINV  = (float*)(ws + 102400);
    int*            CNT   = (int*)(ws + 204800);
    unsigned short* IDX   = (unsigned short*)(ws + 307200);     // 6,553,600
    unsigned short* XW16  = (unsigned short*)(ws + 6860800);    // 6,553,600
    unsigned short* H16   = (unsigned short*)(ws + 13414400);   // 6,553,600
    unsigned short* EMB16 = (unsigned short*)(ws + 19968000);   // 6,553,600
    unsigned short* QKVH  = (unsigned short*)(ws + 26521600);   // 19,660,800

    hipMemsetAsync(CNT, 0, TT * NN * sizeof(int), stream);
    mf_kernel<<<dim3(100), dim3(256), 0, stream>>>(ego, MF);
    edge_kernel<<<dim3(TT * 16), dim3(256), 0, stream>>>(adj, MF, CNT, IDX);
    dinv_kernel<<<dim3(100), dim3(256), 0, stream>>>(MF, CNT, DINV);
    xw1_kernel<<<dim3(12800), dim3(256), 0, stream>>>(x, W1, DINV, XW16);
    agg_kernel<<<dim3(TT * NN), dim3(128), 0, stream>>>(XW16, MF, DINV, CNT, IDX, b1, H16, 1);
    xw2_kernel<<<dim3(200), dim3(256), 0, stream>>>(H16, W2, DINV, XW16);
    agg_kernel<<<dim3(TT * NN), dim3(128), 0, stream>>>(XW16, MF, DINV, CNT, IDX, b2, EMB16, 0);
    proj_kernel<<<dim3(NN * 3), dim3(512), 0, stream>>>(EMB16, Wq, bq, Wk, bk, Wv, bv,
                                                        W_in, b_in, QKVH);
    attn_kernel<<<dim3(NN), dim3(256), 0, stream>>>(QKVH, W_out, b_out, out);
}